// Round 2
// baseline (662.360 us; speedup 1.0000x reference)
//
#include <hip/hip_runtime.h>
#include <stdint.h>
#include <math.h>

#define B_ 4
#define S_ 2048
#define D_ 4096
#define O_ 4096
#define E_ 8
#define R_ 32
#define SCALING 2.0f
#define NOISE_EPS 0.01f

typedef unsigned short u16;
typedef short s16x8 __attribute__((ext_vector_type(8)));   // 8 bf16 = 4 VGPRs
typedef float f32x4 __attribute__((ext_vector_type(4)));

__device__ __forceinline__ float b2f(u16 u) {
  union { unsigned int i; float f; } v; v.i = ((unsigned int)u) << 16; return v.f;
}
__device__ __forceinline__ u16 f2b(float f) {
  union { unsigned int i; float f; } v; v.f = f;
  unsigned int i = v.i;
  return (u16)((i + 0x7FFFu + ((i >> 16) & 1u)) >> 16);  // RNE
}

// dtype-adaptive element access: bf=1 -> bf16, bf=0 -> fp32
__device__ __forceinline__ float ld(const void* p, size_t i, int bf) {
  return bf ? b2f(((const u16*)p)[i]) : ((const float*)p)[i];
}

// ---------------------------------------------------------------------------
// Kernel 0: detect dtype of float inputs by inspecting x's bit patterns.
// ---------------------------------------------------------------------------
__global__ void k_detect(const unsigned int* __restrict__ xw, int* __restrict__ flag) {
  __shared__ int cnt;
  if (threadIdx.x == 0) cnt = 0;
  __syncthreads();
  unsigned int w = xw[threadIdx.x];
  unsigned int e = (w >> 7) & 0xFFu;
  if (e >= 90u && e <= 140u) atomicAdd(&cnt, 1);
  __syncthreads();
  if (threadIdx.x == 0) *flag = (cnt > 48) ? 1 : 0;
}

// ---------------------------------------------------------------------------
// Kernel 1: clean/noise logits. One block per (b,e).
// ---------------------------------------------------------------------------
__global__ __launch_bounds__(256) void k_logits(
    const void* __restrict__ x, const int* __restrict__ eof,
    const void* __restrict__ route_w, const void* __restrict__ noise_w,
    const int* __restrict__ flag, float* __restrict__ wsf) {
  int bf = *flag;
  int be = blockIdx.x;            // 0..31
  int b = be >> 3, e = be & 7;
  size_t xoff = ((size_t)b * S_ + (size_t)eof[b]) * D_;
  size_t woff = (size_t)e * D_;
  float ac = 0.f, an = 0.f;
  for (int d = threadIdx.x; d < D_; d += 256) {
    float xv = ld(x, xoff + d, bf);
    ac += xv * ld(route_w, woff + d, bf);
    an += xv * ld(noise_w, woff + d, bf);
  }
  __shared__ float rc[256], rn[256];
  rc[threadIdx.x] = ac; rn[threadIdx.x] = an;
  __syncthreads();
  for (int s = 128; s > 0; s >>= 1) {
    if (threadIdx.x < (unsigned)s) {
      rc[threadIdx.x] += rc[threadIdx.x + s];
      rn[threadIdx.x] += rn[threadIdx.x + s];
    }
    __syncthreads();
  }
  if (threadIdx.x == 0) { wsf[16 + be] = rc[0]; wsf[48 + be] = rn[0]; }
}

// ---------------------------------------------------------------------------
// Kernel 2: noisy top-2 softmax gates.
// ---------------------------------------------------------------------------
__global__ void k_gates(const void* __restrict__ noise, const int* __restrict__ flag,
                        float* __restrict__ wsf) {
  int bf = *flag;
  int b = threadIdx.x;
  if (b >= B_) return;
  float lg[E_];
  for (int e = 0; e < E_; e++) {
    float c = wsf[16 + b * 8 + e];
    float n = wsf[48 + b * 8 + e];
    float sp = (n > 20.f) ? n : log1pf(expf(n));   // softplus
    lg[e] = c + ld(noise, b * 8 + e, bf) * (sp + NOISE_EPS);
  }
  int i1 = 0; float v1 = lg[0];
  for (int e = 1; e < E_; e++) if (lg[e] > v1) { v1 = lg[e]; i1 = e; }
  int i2 = -1; float v2 = -3.0e38f;
  for (int e = 0; e < E_; e++) if (e != i1 && lg[e] > v2) { v2 = lg[e]; i2 = e; }
  float t = expf(v2 - v1);              // v2 <= v1, stable
  float g1 = 1.f / (1.f + t);
  float g2 = t / (1.f + t);
  for (int e = 0; e < E_; e++) wsf[80 + b * 8 + e] = 0.f;
  wsf[80 + b * 8 + i1] = g1;
  wsf[80 + b * 8 + i2] = g2;
}

// ---------------------------------------------------------------------------
// Kernel 3: Wc[b,o,r] = SCALING * sum_e gates[b,e] * B_w[e,o,r]   (fp32 out)
// ---------------------------------------------------------------------------
__global__ __launch_bounds__(256) void k_wc(
    const void* __restrict__ Bw, const int* __restrict__ flag,
    const float* __restrict__ gates, float* __restrict__ Wc) {
  int bf = *flag;
  int idx = blockIdx.x * 256 + threadIdx.x;     // 0 .. 131071 (groups of 4)
  int b = idx >> 15;
  int u = idx & 32767;                          // 4-elem group within this b
  float g[E_];
#pragma unroll
  for (int e = 0; e < E_; e++) g[e] = gates[b * 8 + e];
  f32x4 acc = {0.f, 0.f, 0.f, 0.f};
  if (bf) {
#pragma unroll
    for (int e = 0; e < E_; e++) {
      ushort4 v = ((const ushort4*)Bw)[(size_t)e * 32768 + u];
      acc[0] += g[e] * b2f(v.x);
      acc[1] += g[e] * b2f(v.y);
      acc[2] += g[e] * b2f(v.z);
      acc[3] += g[e] * b2f(v.w);
    }
  } else {
#pragma unroll
    for (int e = 0; e < E_; e++) {
      f32x4 v = ((const f32x4*)Bw)[(size_t)e * 32768 + u];
      acc += g[e] * v;
    }
  }
  ((f32x4*)Wc)[idx] = acc * SCALING;
}

// ---------------------------------------------------------------------------
// Kernel 3b: zero the shared-projection accumulator (needed by the fp32
// atomic path; harmless for bf16 where k_shared_mfma overwrites).
// 256 blocks x 256 thr x 4 floats = 262144 = B_*S_*R_.
// ---------------------------------------------------------------------------
__global__ void k_zero(float* __restrict__ shw) {
  ((f32x4*)shw)[blockIdx.x * 256 + threadIdx.x] = (f32x4){0.f, 0.f, 0.f, 0.f};
}

// ---------------------------------------------------------------------------
// Kernel 4a (bf16 path): shared[row, r] via MFMA (early-exits on fp32 input).
// ---------------------------------------------------------------------------
__global__ __launch_bounds__(128) void k_shared_mfma(
    const void* __restrict__ xv, const void* __restrict__ Awv,
    const int* __restrict__ flag, float* __restrict__ sh_out) {
  if (!*flag) return;                 // fp32 inputs -> v2 kernel handles
  const u16* x  = (const u16*)xv;
  const u16* Aw = (const u16*)Awv;
  int lane = threadIdx.x & 63;
  int wave = threadIdx.x >> 6;        // 0..1
  int m = lane & 15, kg = lane >> 4;  // fragment row / k-group
  int row0 = (blockIdx.x * 2 + wave) * 16;
  const u16* xp  = x  + (size_t)(row0 + m) * D_ + kg * 8;
  const u16* a0p = Aw + (size_t)m * D_ + kg * 8;          // r = 0..15
  const u16* a1p = Aw + (size_t)(m + 16) * D_ + kg * 8;   // r = 16..31
  f32x4 acc0 = {0.f, 0.f, 0.f, 0.f};
  f32x4 acc1 = {0.f, 0.f, 0.f, 0.f};
#pragma unroll 4
  for (int k0 = 0; k0 < D_; k0 += 32) {
    s16x8 a  = *(const s16x8*)(xp + k0);
    s16x8 b0 = *(const s16x8*)(a0p + k0);
    s16x8 b1 = *(const s16x8*)(a1p + k0);
    acc0 = __builtin_amdgcn_mfma_f32_16x16x32_bf16(a, b0, acc0, 0, 0, 0);
    acc1 = __builtin_amdgcn_mfma_f32_16x16x32_bf16(a, b1, acc1, 0, 0, 0);
  }
  int col = lane & 15;
  int rbase = (lane >> 4) * 4;
  float* outp = sh_out + (size_t)row0 * R_;
#pragma unroll
  for (int j = 0; j < 4; j++) {
    outp[(size_t)(rbase + j) * R_ + col]      = acc0[j];
    outp[(size_t)(rbase + j) * R_ + col + 16] = acc1[j];
  }
}

// ---------------------------------------------------------------------------
// Kernel 4b (fp32 path, v2): lane = row. Each lane streams its own contiguous
// x row segment from global (x has zero reuse -> no LDS at all); A_w reads are
// wave-uniform (scalarizable to s_load / single-line loads, L1-resident).
// Grid: 128 row-groups (64 rows) x 16 d-chunks (256) = 2048 one-wave blocks.
// d-partials combined via atomicAdd into pre-zeroed shw.
// ---------------------------------------------------------------------------
__global__ __launch_bounds__(64, 4) void k_shared_f32v2(
    const float* __restrict__ x, const float* __restrict__ Aw,
    const int* __restrict__ flag, float* __restrict__ shw) {
  if (*flag) return;                  // bf16 inputs -> MFMA kernel handles
  int lane = threadIdx.x;             // 0..63
  int rowgrp = blockIdx.x >> 4;       // 0..127
  int ds = blockIdx.x & 15;           // d-chunk 0..15
  int row = rowgrp * 64 + lane;
  const float* xp = x + (size_t)row * D_ + ds * 256;
  const float* ap = Aw + ds * 256;    // A[r][k] = ap[r*D_ + k] (wave-uniform)
  float acc[R_];
#pragma unroll
  for (int r = 0; r < R_; r++) acc[r] = 0.f;
  for (int kk = 0; kk < 256; kk += 16) {
    f32x4 xv0 = *(const f32x4*)(xp + kk);
    f32x4 xv1 = *(const f32x4*)(xp + kk + 4);
    f32x4 xv2 = *(const f32x4*)(xp + kk + 8);
    f32x4 xv3 = *(const f32x4*)(xp + kk + 12);
#pragma unroll
    for (int r = 0; r < R_; r++) {
      const float* ar = ap + (size_t)r * D_ + kk;
      f32x4 a0 = *(const f32x4*)(ar);
      f32x4 a1 = *(const f32x4*)(ar + 4);
      f32x4 a2 = *(const f32x4*)(ar + 8);
      f32x4 a3 = *(const f32x4*)(ar + 12);
      float s = acc[r];
      s = fmaf(xv0[0], a0[0], s); s = fmaf(xv0[1], a0[1], s);
      s = fmaf(xv0[2], a0[2], s); s = fmaf(xv0[3], a0[3], s);
      s = fmaf(xv1[0], a1[0], s); s = fmaf(xv1[1], a1[1], s);
      s = fmaf(xv1[2], a1[2], s); s = fmaf(xv1[3], a1[3], s);
      s = fmaf(xv2[0], a2[0], s); s = fmaf(xv2[1], a2[1], s);
      s = fmaf(xv2[2], a2[2], s); s = fmaf(xv2[3], a2[3], s);
      s = fmaf(xv3[0], a3[0], s); s = fmaf(xv3[1], a3[1], s);
      s = fmaf(xv3[2], a3[2], s); s = fmaf(xv3[3], a3[3], s);
      acc[r] = s;
    }
  }
  float* op = shw + (size_t)row * R_;
#pragma unroll
  for (int r = 0; r < R_; r++) atomicAdd(op + r, acc[r]);
}

// ---------------------------------------------------------------------------
// Kernel 5: out[row, o] = sum_r shared[row, r] * Wc[b, o, r]
// Block tile: 32 rows x 256 cols; thread tile: 8 rows x 4 cols (32 fp32 acc).
// Wc read directly from global (panel is 32 KB, L1/L2-resident, reused 4x per
// thread); sh staged in a tiny LDS buffer read via wave-uniform broadcast.
// ---------------------------------------------------------------------------
__global__ __launch_bounds__(256) void k_out(
    const float* __restrict__ shw, const float* __restrict__ Wc,
    const int* __restrict__ flag, void* __restrict__ out) {
  __shared__ float shs[32][36];    // [row-row0][r], 144 B stride (16B-aligned)
  int bf = *flag;
  int t = threadIdx.x;
  int o0   = (blockIdx.x & 15) * 256;
  int row0 = (blockIdx.x >> 4) * 32;
  int b = row0 >> 11;
  // stage sh: 8 threads per row
  {
    int row = t >> 3, rc = (t & 7) * 4;
    *(f32x4*)&shs[row][rc] = *(const f32x4*)(shw + (size_t)(row0 + row) * R_ + rc);
  }
  __syncthreads();
  int o4 = (t & 63) * 4;           // first of this thread's 4 cols
  int rbase = (t >> 6) * 8;        // row group within tile (wave-uniform)
  const float* wp = Wc + (size_t)b * (O_ * R_) + (size_t)(o0 + o4) * R_;
  f32x4 acc[8];
#pragma unroll
  for (int i = 0; i < 8; i++) acc[i] = (f32x4){0.f, 0.f, 0.f, 0.f};
#pragma unroll
  for (int rc = 0; rc < R_; rc += 4) {
    f32x4 w0 = *(const f32x4*)(wp + 0 * R_ + rc);
    f32x4 w1 = *(const f32x4*)(wp + 1 * R_ + rc);
    f32x4 w2 = *(const f32x4*)(wp + 2 * R_ + rc);
    f32x4 w3 = *(const f32x4*)(wp + 3 * R_ + rc);
#pragma unroll
    for (int i = 0; i < 8; i++) {
      f32x4 a = *(const f32x4*)&shs[rbase + i][rc];   // uniform broadcast
      float s0 = acc[i][0], s1 = acc[i][1], s2 = acc[i][2], s3 = acc[i][3];
      s0 = fmaf(a[0], w0[0], s0); s0 = fmaf(a[1], w0[1], s0);
      s0 = fmaf(a[2], w0[2], s0); s0 = fmaf(a[3], w0[3], s0);
      s1 = fmaf(a[0], w1[0], s1); s1 = fmaf(a[1], w1[1], s1);
      s1 = fmaf(a[2], w1[2], s1); s1 = fmaf(a[3], w1[3], s1);
      s2 = fmaf(a[0], w2[0], s2); s2 = fmaf(a[1], w2[1], s2);
      s2 = fmaf(a[2], w2[2], s2); s2 = fmaf(a[3], w2[3], s2);
      s3 = fmaf(a[0], w3[0], s3); s3 = fmaf(a[1], w3[1], s3);
      s3 = fmaf(a[2], w3[2], s3); s3 = fmaf(a[3], w3[3], s3);
      acc[i][0] = s0; acc[i][1] = s1; acc[i][2] = s2; acc[i][3] = s3;
    }
  }
#pragma unroll
  for (int i = 0; i < 8; i++) {
    size_t off = (size_t)(row0 + rbase + i) * O_ + o0 + o4;
    if (bf) {
      ushort4 v;
      v.x = f2b(acc[i][0]); v.y = f2b(acc[i][1]);
      v.z = f2b(acc[i][2]); v.w = f2b(acc[i][3]);
      *(ushort4*)((u16*)out + off) = v;
    } else {
      *(f32x4*)((float*)out + off) = acc[i];
    }
  }
}

// ---------------------------------------------------------------------------
extern "C" void kernel_launch(void* const* d_in, const int* in_sizes, int n_in,
                              void* d_out, int out_size, void* d_ws, size_t ws_size,
                              hipStream_t stream) {
  const void* x       = d_in[0];                 // [4,2048,4096] f32 or bf16
  const int*  eof     = (const int*)d_in[1];     // [4]
  const void* noise   = d_in[2];                 // [4,8]
  const void* Aw      = d_in[3];                 // [32,4096]
  const void* Bw      = d_in[4];                 // [8,4096,32]
  const void* route_w = d_in[5];                 // [8,4096]
  const void* noise_w = d_in[6];                 // [8,4096]
  float* wsf = (float*)d_ws;
  int* flag = (int*)wsf;                         // wsf[0]
  // ws layout (floats): [0] flag | [16,48) clean | [48,80) noise logits |
  // [80,112) gates | [112, +524288) Wc | then 262144 floats of shared
  float* gates = wsf + 80;
  float* Wc    = wsf + 112;
  float* shw   = wsf + 112 + (size_t)B_ * O_ * R_;

  k_detect<<<1, 64, 0, stream>>>((const unsigned int*)x, flag);
  k_logits<<<B_ * E_, 256, 0, stream>>>(x, eof, route_w, noise_w, flag, wsf);
  k_gates<<<1, 64, 0, stream>>>(noise, flag, wsf);
  k_wc<<<(B_ * O_ * R_ / 4) / 256, 256, 0, stream>>>(Bw, flag, gates, Wc);
  k_zero<<<(B_ * S_ * R_ / 4) / 256, 256, 0, stream>>>(shw);
  k_shared_mfma<<<(B_ * S_) / 32, 128, 0, stream>>>(x, Aw, flag, shw);
  k_shared_f32v2<<<(S_ * B_ / 64) * 16, 64, 0, stream>>>(
      (const float*)x, (const float*)Aw, flag, shw);
  k_out<<<((B_ * S_) / 32) * (O_ / 256), 256, 0, stream>>>(shw, Wc, flag, d_out);
}

// Round 3
// 318.459 us; speedup vs baseline: 2.0799x; 2.0799x over previous
//
#include <hip/hip_runtime.h>
#include <stdint.h>
#include <math.h>

#define B_ 4
#define S_ 2048
#define D_ 4096
#define O_ 4096
#define E_ 8
#define R_ 32
#define SCALING 2.0f
#define NOISE_EPS 0.01f

typedef unsigned short u16;
typedef short s16x8 __attribute__((ext_vector_type(8)));   // 8 bf16 = 4 VGPRs
typedef float f32x4 __attribute__((ext_vector_type(4)));

__device__ __forceinline__ float b2f(u16 u) {
  union { unsigned int i; float f; } v; v.i = ((unsigned int)u) << 16; return v.f;
}
__device__ __forceinline__ u16 f2b(float f) {
  union { unsigned int i; float f; } v; v.f = f;
  unsigned int i = v.i;
  return (u16)((i + 0x7FFFu + ((i >> 16) & 1u)) >> 16);  // RNE
}
// two-term bf16 split: f = b2f(h) + b2f(l) + O(2^-17 |f|)
__device__ __forceinline__ void split2(float f, u16* h, u16* l) {
  u16 hi = f2b(f);
  *h = hi;
  *l = f2b(f - b2f(hi));   // f - b2f(hi) is exact in fp32
}

// dtype-adaptive element access: bf=1 -> bf16, bf=0 -> fp32
__device__ __forceinline__ float ld(const void* p, size_t i, int bf) {
  return bf ? b2f(((const u16*)p)[i]) : ((const float*)p)[i];
}

// ---------------------------------------------------------------------------
// Kernel 0: detect dtype of float inputs by inspecting x's bit patterns.
// ---------------------------------------------------------------------------
__global__ void k_detect(const unsigned int* __restrict__ xw, int* __restrict__ flag) {
  __shared__ int cnt;
  if (threadIdx.x == 0) cnt = 0;
  __syncthreads();
  unsigned int w = xw[threadIdx.x];
  unsigned int e = (w >> 7) & 0xFFu;
  if (e >= 90u && e <= 140u) atomicAdd(&cnt, 1);
  __syncthreads();
  if (threadIdx.x == 0) *flag = (cnt > 48) ? 1 : 0;
}

// ---------------------------------------------------------------------------
// Kernel 1: clean/noise logits. One block per (b,e).
// ---------------------------------------------------------------------------
__global__ __launch_bounds__(256) void k_logits(
    const void* __restrict__ x, const int* __restrict__ eof,
    const void* __restrict__ route_w, const void* __restrict__ noise_w,
    const int* __restrict__ flag, float* __restrict__ wsf) {
  int bf = *flag;
  int be = blockIdx.x;            // 0..31
  int b = be >> 3, e = be & 7;
  size_t xoff = ((size_t)b * S_ + (size_t)eof[b]) * D_;
  size_t woff = (size_t)e * D_;
  float ac = 0.f, an = 0.f;
  for (int d = threadIdx.x; d < D_; d += 256) {
    float xv = ld(x, xoff + d, bf);
    ac += xv * ld(route_w, woff + d, bf);
    an += xv * ld(noise_w, woff + d, bf);
  }
  __shared__ float rc[256], rn[256];
  rc[threadIdx.x] = ac; rn[threadIdx.x] = an;
  __syncthreads();
  for (int s = 128; s > 0; s >>= 1) {
    if (threadIdx.x < (unsigned)s) {
      rc[threadIdx.x] += rc[threadIdx.x + s];
      rn[threadIdx.x] += rn[threadIdx.x + s];
    }
    __syncthreads();
  }
  if (threadIdx.x == 0) { wsf[16 + be] = rc[0]; wsf[48 + be] = rn[0]; }
}

// ---------------------------------------------------------------------------
// Kernel 2: noisy top-2 softmax gates.
// ---------------------------------------------------------------------------
__global__ void k_gates(const void* __restrict__ noise, const int* __restrict__ flag,
                        float* __restrict__ wsf) {
  int bf = *flag;
  int b = threadIdx.x;
  if (b >= B_) return;
  float lg[E_];
  for (int e = 0; e < E_; e++) {
    float c = wsf[16 + b * 8 + e];
    float n = wsf[48 + b * 8 + e];
    float sp = (n > 20.f) ? n : log1pf(expf(n));   // softplus
    lg[e] = c + ld(noise, b * 8 + e, bf) * (sp + NOISE_EPS);
  }
  int i1 = 0; float v1 = lg[0];
  for (int e = 1; e < E_; e++) if (lg[e] > v1) { v1 = lg[e]; i1 = e; }
  int i2 = -1; float v2 = -3.0e38f;
  for (int e = 0; e < E_; e++) if (e != i1 && lg[e] > v2) { v2 = lg[e]; i2 = e; }
  float t = expf(v2 - v1);              // v2 <= v1, stable
  float g1 = 1.f / (1.f + t);
  float g2 = t / (1.f + t);
  for (int e = 0; e < E_; e++) wsf[80 + b * 8 + e] = 0.f;
  wsf[80 + b * 8 + i1] = g1;
  wsf[80 + b * 8 + i2] = g2;
}

// ---------------------------------------------------------------------------
// Kernel 3: decompose A_w (fp32 path only) into bf16 hi/lo planes.
// ---------------------------------------------------------------------------
__global__ __launch_bounds__(256) void k_prepA(
    const float* __restrict__ Aw, const int* __restrict__ flag,
    u16* __restrict__ A2h, u16* __restrict__ A2l) {
  if (*flag) return;                      // bf16 inputs: A_w used directly
  int idx = blockIdx.x * 256 + threadIdx.x;   // quads, 32768 total
  f32x4 v = ((const f32x4*)Aw)[idx];
  ushort4 h, l;
  split2(v[0], &h.x, &l.x); split2(v[1], &h.y, &l.y);
  split2(v[2], &h.z, &l.z); split2(v[3], &h.w, &l.w);
  ((ushort4*)A2h)[idx] = h;
  ((ushort4*)A2l)[idx] = l;
}

// ---------------------------------------------------------------------------
// Kernel 4: Wc[b,o,r] = SCALING * sum_e gates[b,e] * B_w[e,o,r],
// emitted directly as bf16 hi/lo planes for the MFMA epilogue GEMM.
// ---------------------------------------------------------------------------
__global__ __launch_bounds__(256) void k_wc(
    const void* __restrict__ Bw, const int* __restrict__ flag,
    const float* __restrict__ gates, u16* __restrict__ Wc2h,
    u16* __restrict__ Wc2l) {
  int bf = *flag;
  int idx = blockIdx.x * 256 + threadIdx.x;     // quads, 131072 total
  int b = idx >> 15;
  int u = idx & 32767;
  float g[E_];
#pragma unroll
  for (int e = 0; e < E_; e++) g[e] = gates[b * 8 + e];
  f32x4 acc = {0.f, 0.f, 0.f, 0.f};
  if (bf) {
#pragma unroll
    for (int e = 0; e < E_; e++) {
      ushort4 v = ((const ushort4*)Bw)[(size_t)e * 32768 + u];
      acc[0] += g[e] * b2f(v.x);
      acc[1] += g[e] * b2f(v.y);
      acc[2] += g[e] * b2f(v.z);
      acc[3] += g[e] * b2f(v.w);
    }
  } else {
#pragma unroll
    for (int e = 0; e < E_; e++) {
      f32x4 v = ((const f32x4*)Bw)[(size_t)e * 32768 + u];
      acc += g[e] * v;
    }
  }
  acc *= SCALING;
  ushort4 h, l;
  split2(acc[0], &h.x, &l.x); split2(acc[1], &h.y, &l.y);
  split2(acc[2], &h.z, &l.z); split2(acc[3], &h.w, &l.w);
  ((ushort4*)Wc2h)[idx] = h;
  ((ushort4*)Wc2l)[idx] = l;
}

// ---------------------------------------------------------------------------
// Kernel 5: shared[row, r] = sum_d x[row, d] * A_w[r, d] via MFMA.
// Block = 4 waves on the SAME 16 rows; wave w covers d-chunk [w*1024, +1024).
// fp32 path: x split on the fly to bf16 hi/lo, 3-product MFMA (hh+hl+lh).
// bf16 path: direct fragment loads, 1 product.
// Wave partials reduced through LDS (fp32, deterministic), then decomposed
// to sh2h/sh2l bf16 planes for the epilogue GEMM.
// Fragment layout (m89/m91-verified family): A-op lane l -> row=l&15,
// k=(l>>4)*8+j; B-op lane l -> col=l&15, same k; C/D col=lane&15,
// row=(lane>>4)*4+reg.
// ---------------------------------------------------------------------------
__global__ __launch_bounds__(256) void k_sharedM(
    const void* __restrict__ xv, const void* __restrict__ Awv,
    const u16* __restrict__ A2h, const u16* __restrict__ A2l,
    const int* __restrict__ flag, u16* __restrict__ sh2h,
    u16* __restrict__ sh2l) {
  __shared__ float red[4][512];          // [wave][row*32 + r]
  int bf = *flag;
  int lane = threadIdx.x & 63;
  int wave = threadIdx.x >> 6;           // d-chunk owner
  int m = lane & 15, kg = lane >> 4;
  int row0 = blockIdx.x * 16;
  int kbase = wave * 1024 + kg * 8;
  f32x4 acc0 = {0.f, 0.f, 0.f, 0.f};
  f32x4 acc1 = {0.f, 0.f, 0.f, 0.f};
  if (bf) {
    const u16* xp = (const u16*)xv + (size_t)(row0 + m) * D_ + kbase;
    const u16* a0 = (const u16*)Awv + (size_t)m * D_ + kbase;
    const u16* a1 = (const u16*)Awv + (size_t)(m + 16) * D_ + kbase;
#pragma unroll 4
    for (int k0 = 0; k0 < 1024; k0 += 32) {
      s16x8 a  = *(const s16x8*)(xp + k0);
      s16x8 b0 = *(const s16x8*)(a0 + k0);
      s16x8 b1 = *(const s16x8*)(a1 + k0);
      acc0 = __builtin_amdgcn_mfma_f32_16x16x32_bf16(a, b0, acc0, 0, 0, 0);
      acc1 = __builtin_amdgcn_mfma_f32_16x16x32_bf16(a, b1, acc1, 0, 0, 0);
    }
  } else {
    const float* xp = (const float*)xv + (size_t)(row0 + m) * D_ + kbase;
    const u16* h0 = A2h + (size_t)m * D_ + kbase;
    const u16* l0 = A2l + (size_t)m * D_ + kbase;
    const u16* h1 = A2h + (size_t)(m + 16) * D_ + kbase;
    const u16* l1 = A2l + (size_t)(m + 16) * D_ + kbase;
#pragma unroll 2
    for (int k0 = 0; k0 < 1024; k0 += 32) {
      f32x4 x0 = *(const f32x4*)(xp + k0);
      f32x4 x1 = *(const f32x4*)(xp + k0 + 4);
      s16x8 xh, xl;
      u16 hh, ll;
#pragma unroll
      for (int j = 0; j < 4; j++) {
        split2(x0[j], &hh, &ll); xh[j] = (short)hh; xl[j] = (short)ll;
        split2(x1[j], &hh, &ll); xh[j + 4] = (short)hh; xl[j + 4] = (short)ll;
      }
      s16x8 bh0 = *(const s16x8*)(h0 + k0);
      s16x8 bl0 = *(const s16x8*)(l0 + k0);
      s16x8 bh1 = *(const s16x8*)(h1 + k0);
      s16x8 bl1 = *(const s16x8*)(l1 + k0);
      acc0 = __builtin_amdgcn_mfma_f32_16x16x32_bf16(xh, bh0, acc0, 0, 0, 0);
      acc0 = __builtin_amdgcn_mfma_f32_16x16x32_bf16(xh, bl0, acc0, 0, 0, 0);
      acc0 = __builtin_amdgcn_mfma_f32_16x16x32_bf16(xl, bh0, acc0, 0, 0, 0);
      acc1 = __builtin_amdgcn_mfma_f32_16x16x32_bf16(xh, bh1, acc1, 0, 0, 0);
      acc1 = __builtin_amdgcn_mfma_f32_16x16x32_bf16(xh, bl1, acc1, 0, 0, 0);
      acc1 = __builtin_amdgcn_mfma_f32_16x16x32_bf16(xl, bh1, acc1, 0, 0, 0);
    }
  }
  // deposit wave partials: C layout col=lane&15 (r), row=(lane>>4)*4+j
  int crow = (lane >> 4) * 4, ccol = lane & 15;
#pragma unroll
  for (int j = 0; j < 4; j++) {
    red[wave][(crow + j) * 32 + ccol]      = acc0[j];
    red[wave][(crow + j) * 32 + ccol + 16] = acc1[j];
  }
  __syncthreads();
  // reduce 4 planes, split to bf16 hi/lo; 2 elems per thread (512 total)
  int t = threadIdx.x;
#pragma unroll
  for (int q = 0; q < 2; q++) {
    int e = t + q * 256;
    float s = red[0][e] + red[1][e] + red[2][e] + red[3][e];
    u16 h, l;
    split2(s, &h, &l);
    sh2h[(size_t)row0 * R_ + e] = h;
    sh2l[(size_t)row0 * R_ + e] = l;
  }
}

// ---------------------------------------------------------------------------
// Kernel 6: out[row, o] = sum_r shared[row, r] * Wc[b, o, r] via MFMA.
// K = R = 32 -> one 16x16x32 step (x3 split products) per 16x16 tile.
// Wave = 16 rows x 128 o (8 tiles); block = 4 waves = 64 rows x 128 o.
// ---------------------------------------------------------------------------
__global__ __launch_bounds__(256) void k_outM(
    const u16* __restrict__ sh2h, const u16* __restrict__ sh2l,
    const u16* __restrict__ Wc2h, const u16* __restrict__ Wc2l,
    const int* __restrict__ flag, void* __restrict__ out) {
  int bf = *flag;
  int lane = threadIdx.x & 63;
  int wave = threadIdx.x >> 6;
  int rb = blockIdx.x >> 5;       // 0..127
  int ob = blockIdx.x & 31;       // 0..31
  int row0 = rb * 64 + wave * 16;
  int b = row0 >> 11;
  int m = lane & 15, kg = lane >> 4;
  // A fragments: 16 rows x 32 r of shared (hi/lo)
  s16x8 Ah = *(const s16x8*)(sh2h + (size_t)(row0 + m) * R_ + kg * 8);
  s16x8 Al = *(const s16x8*)(sh2l + (size_t)(row0 + m) * R_ + kg * 8);
  const u16* wh = Wc2h + (size_t)b * (O_ * R_) + (size_t)(ob * 128 + m) * R_ + kg * 8;
  const u16* wl = Wc2l + (size_t)b * (O_ * R_) + (size_t)(ob * 128 + m) * R_ + kg * 8;
  int crow = (lane >> 4) * 4;
#pragma unroll
  for (int ot = 0; ot < 8; ot++) {
    s16x8 Bh = *(const s16x8*)(wh + (size_t)ot * 16 * R_);
    s16x8 Bl = *(const s16x8*)(wl + (size_t)ot * 16 * R_);
    f32x4 acc = {0.f, 0.f, 0.f, 0.f};
    acc = __builtin_amdgcn_mfma_f32_16x16x32_bf16(Ah, Bh, acc, 0, 0, 0);
    acc = __builtin_amdgcn_mfma_f32_16x16x32_bf16(Ah, Bl, acc, 0, 0, 0);
    acc = __builtin_amdgcn_mfma_f32_16x16x32_bf16(Al, Bh, acc, 0, 0, 0);
    int o = ob * 128 + ot * 16 + m;              // C col = lane&15
    if (bf) {
      u16* op = (u16*)out + (size_t)(row0 + crow) * O_ + o;
#pragma unroll
      for (int j = 0; j < 4; j++) op[(size_t)j * O_] = f2b(acc[j]);
    } else {
      float* op = (float*)out + (size_t)(row0 + crow) * O_ + o;
#pragma unroll
      for (int j = 0; j < 4; j++) op[(size_t)j * O_] = acc[j];
    }
  }
}

// ---------------------------------------------------------------------------
extern "C" void kernel_launch(void* const* d_in, const int* in_sizes, int n_in,
                              void* d_out, int out_size, void* d_ws, size_t ws_size,
                              hipStream_t stream) {
  const void* x       = d_in[0];                 // [4,2048,4096] f32 or bf16
  const int*  eof     = (const int*)d_in[1];     // [4]
  const void* noise   = d_in[2];                 // [4,8]
  const void* Aw      = d_in[3];                 // [32,4096]
  const void* Bw      = d_in[4];                 // [8,4096,32]
  const void* route_w = d_in[5];                 // [8,4096]
  const void* noise_w = d_in[6];                 // [8,4096]
  float* wsf = (float*)d_ws;
  int* flag = (int*)wsf;                         // wsf[0]
  float* gates = wsf + 80;
  // u16 regions after the 112-float scalar header (448 B, 16B-aligned)
  u16* Wc2h = (u16*)(wsf + 112);                 // 524288 u16 = 1 MB
  u16* Wc2l = Wc2h + (size_t)B_ * O_ * R_;       // 1 MB
  u16* A2h  = Wc2l + (size_t)B_ * O_ * R_;       // 131072 u16 = 256 KB
  u16* A2l  = A2h + (size_t)R_ * D_;             // 256 KB
  u16* sh2h = A2l + (size_t)R_ * D_;             // 262144 u16 = 512 KB
  u16* sh2l = sh2h + (size_t)B_ * S_ * R_;       // 512 KB

  k_detect<<<1, 64, 0, stream>>>((const unsigned int*)x, flag);
  k_logits<<<B_ * E_, 256, 0, stream>>>(x, eof, route_w, noise_w, flag, wsf);
  k_gates<<<1, 64, 0, stream>>>(noise, flag, wsf);
  k_prepA<<<(R_ * D_ / 4) / 256, 256, 0, stream>>>((const float*)Aw, flag, A2h, A2l);
  k_wc<<<(B_ * O_ * R_ / 4) / 256, 256, 0, stream>>>(Bw, flag, gates, Wc2h, Wc2l);
  k_sharedM<<<(B_ * S_) / 16, 256, 0, stream>>>(x, Aw, A2h, A2l, flag, sh2h, sh2l);
  k_outM<<<((B_ * S_) / 64) * (O_ / 128), 256, 0, stream>>>(
      sh2h, sh2l, Wc2h, Wc2l, flag, d_out);
}

// Round 5
// 315.142 us; speedup vs baseline: 2.1018x; 1.0105x over previous
//
#include <hip/hip_runtime.h>
#include <stdint.h>
#include <math.h>

#define B_ 4
#define S_ 2048
#define D_ 4096
#define O_ 4096
#define E_ 8
#define R_ 32
#define SCALING 2.0f
#define NOISE_EPS 0.01f

typedef unsigned short u16;
typedef short s16x8 __attribute__((ext_vector_type(8)));   // 8 bf16 = 4 VGPRs
typedef float f32x4 __attribute__((ext_vector_type(4)));

__device__ __forceinline__ float b2f(u16 u) {
  union { unsigned int i; float f; } v; v.i = ((unsigned int)u) << 16; return v.f;
}
__device__ __forceinline__ u16 f2b(float f) {
  union { unsigned int i; float f; } v; v.f = f;
  unsigned int i = v.i;
  return (u16)((i + 0x7FFFu + ((i >> 16) & 1u)) >> 16);  // RNE
}
// two-term bf16 split: f = b2f(h) + b2f(l) + O(2^-17 |f|)
__device__ __forceinline__ void split2(float f, u16* h, u16* l) {
  u16 hi = f2b(f);
  *h = hi;
  *l = f2b(f - b2f(hi));   // f - b2f(hi) is exact in fp32
}

__device__ __forceinline__ float ld(const void* p, size_t i, int bf) {
  return bf ? b2f(((const u16*)p)[i]) : ((const float*)p)[i];
}

// ---------------------------------------------------------------------------
// Kernel 0: detect dtype of float inputs by inspecting x's bit patterns.
// ---------------------------------------------------------------------------
__global__ void k_detect(const unsigned int* __restrict__ xw, int* __restrict__ flag) {
  __shared__ int cnt;
  if (threadIdx.x == 0) cnt = 0;
  __syncthreads();
  unsigned int w = xw[threadIdx.x];
  unsigned int e = (w >> 7) & 0xFFu;
  if (e >= 90u && e <= 140u) atomicAdd(&cnt, 1);
  __syncthreads();
  if (threadIdx.x == 0) *flag = (cnt > 48) ? 1 : 0;
}

// ---------------------------------------------------------------------------
// Kernel 1: clean/noise logits. One block per (b,e).
// ---------------------------------------------------------------------------
__global__ __launch_bounds__(256) void k_logits(
    const void* __restrict__ x, const int* __restrict__ eof,
    const void* __restrict__ route_w, const void* __restrict__ noise_w,
    const int* __restrict__ flag, float* __restrict__ wsf) {
  int bf = *flag;
  int be = blockIdx.x;            // 0..31
  int b = be >> 3, e = be & 7;
  size_t xoff = ((size_t)b * S_ + (size_t)eof[b]) * D_;
  size_t woff = (size_t)e * D_;
  float ac = 0.f, an = 0.f;
  for (int d = threadIdx.x; d < D_; d += 256) {
    float xv = ld(x, xoff + d, bf);
    ac += xv * ld(route_w, woff + d, bf);
    an += xv * ld(noise_w, woff + d, bf);
  }
  __shared__ float rc[256], rn[256];
  rc[threadIdx.x] = ac; rn[threadIdx.x] = an;
  __syncthreads();
  for (int s = 128; s > 0; s >>= 1) {
    if (threadIdx.x < (unsigned)s) {
      rc[threadIdx.x] += rc[threadIdx.x + s];
      rn[threadIdx.x] += rn[threadIdx.x + s];
    }
    __syncthreads();
  }
  if (threadIdx.x == 0) { wsf[16 + be] = rc[0]; wsf[48 + be] = rn[0]; }
}

// ---------------------------------------------------------------------------
// Kernel 2: noisy top-2 softmax gates.
// ---------------------------------------------------------------------------
__global__ void k_gates(const void* __restrict__ noise, const int* __restrict__ flag,
                        float* __restrict__ wsf) {
  int bf = *flag;
  int b = threadIdx.x;
  if (b >= B_) return;
  float lg[E_];
  for (int e = 0; e < E_; e++) {
    float c = wsf[16 + b * 8 + e];
    float n = wsf[48 + b * 8 + e];
    float sp = (n > 20.f) ? n : log1pf(expf(n));   // softplus
    lg[e] = c + ld(noise, b * 8 + e, bf) * (sp + NOISE_EPS);
  }
  int i1 = 0; float v1 = lg[0];
  for (int e = 1; e < E_; e++) if (lg[e] > v1) { v1 = lg[e]; i1 = e; }
  int i2 = -1; float v2 = -3.0e38f;
  for (int e = 0; e < E_; e++) if (e != i1 && lg[e] > v2) { v2 = lg[e]; i2 = e; }
  float t = expf(v2 - v1);              // v2 <= v1, stable
  float g1 = 1.f / (1.f + t);
  float g2 = t / (1.f + t);
  for (int e = 0; e < E_; e++) wsf[80 + b * 8 + e] = 0.f;
  wsf[80 + b * 8 + i1] = g1;
  wsf[80 + b * 8 + i2] = g2;
}

// ---------------------------------------------------------------------------
// Kernel 3: decompose A_w (fp32 path) into bf16 hi/lo planes in PREPACKED
// fragment order: Ap[k32idx][half][lane][8], so k_sharedM's B-operand loads
// are base + lane*8 (fully coalesced).
//   r = half*16 + (lane&15), d = k32idx*32 + (lane>>4)*8 + j
// ---------------------------------------------------------------------------
__global__ __launch_bounds__(256) void k_prepA(
    const float* __restrict__ Aw, const int* __restrict__ flag,
    u16* __restrict__ Aph, u16* __restrict__ Apl) {
  if (*flag) return;                      // bf16 inputs: A_w used directly
  int flat = blockIdx.x * 256 + threadIdx.x;   // 0 .. 16383
  int k32idx = flat >> 7;
  int rem = flat & 127;
  int h = rem >> 6;
  int lane = rem & 63;
  int r = h * 16 + (lane & 15);
  int d = k32idx * 32 + (lane >> 4) * 8;
  const float* src = Aw + (size_t)r * D_ + d;
  f32x4 v0 = *(const f32x4*)src;
  f32x4 v1 = *(const f32x4*)(src + 4);
  ushort4 h0, l0, h1, l1;
  split2(v0[0], &h0.x, &l0.x); split2(v0[1], &h0.y, &l0.y);
  split2(v0[2], &h0.z, &l0.z); split2(v0[3], &h0.w, &l0.w);
  split2(v1[0], &h1.x, &l1.x); split2(v1[1], &h1.y, &l1.y);
  split2(v1[2], &h1.z, &l1.z); split2(v1[3], &h1.w, &l1.w);
  *(ushort4*)(Aph + (size_t)flat * 8)     = h0;
  *(ushort4*)(Aph + (size_t)flat * 8 + 4) = h1;
  *(ushort4*)(Apl + (size_t)flat * 8)     = l0;
  *(ushort4*)(Apl + (size_t)flat * 8 + 4) = l1;
}

// ---------------------------------------------------------------------------
// Kernel 4: Wc[b,o,r] = SCALING * sum_e gates[b,e]*B_w[e,o,r], emitted as
// bf16 hi/lo planes in PREPACKED fragment order:
//   Wp[b][ot][lane][8], ot = o>>4, lane = (r>>3)*16 + (o&15), j = r&7
// Thread handles one r-quad: idx -> b, o, rq (4 r's).
// ---------------------------------------------------------------------------
__global__ __launch_bounds__(256) void k_wc(
    const void* __restrict__ Bw, const int* __restrict__ flag,
    const float* __restrict__ gates, u16* __restrict__ Wph,
    u16* __restrict__ Wpl) {
  int bf = *flag;
  int idx = blockIdx.x * 256 + threadIdx.x;     // 0 .. 131071
  int b = idx >> 15;
  int u = idx & 32767;                          // o*8 + rq
  int o = u >> 3, rq = u & 7;
  float g[E_];
#pragma unroll
  for (int e = 0; e < E_; e++) g[e] = gates[b * 8 + e];
  f32x4 acc = {0.f, 0.f, 0.f, 0.f};
  if (bf) {
#pragma unroll
    for (int e = 0; e < E_; e++) {
      ushort4 v = ((const ushort4*)Bw)[(size_t)e * 32768 + u];
      acc[0] += g[e] * b2f(v.x);
      acc[1] += g[e] * b2f(v.y);
      acc[2] += g[e] * b2f(v.z);
      acc[3] += g[e] * b2f(v.w);
    }
  } else {
#pragma unroll
    for (int e = 0; e < E_; e++) {
      f32x4 v = ((const f32x4*)Bw)[(size_t)e * 32768 + u];
      acc += g[e] * v;
    }
  }
  acc *= SCALING;
  ushort4 h, l;
  split2(acc[0], &h.x, &l.x); split2(acc[1], &h.y, &l.y);
  split2(acc[2], &h.z, &l.z); split2(acc[3], &h.w, &l.w);
  int ot = o >> 4;
  int lane = ((rq >> 1) * 16) + (o & 15);
  size_t base = (((size_t)b * 256 + ot) * 64 + lane) * 8 + (rq & 1) * 4;
  *(ushort4*)(Wph + base) = h;
  *(ushort4*)(Wpl + base) = l;
}

// ---------------------------------------------------------------------------
// Kernel 5: shared[row, r] = sum_d x[row, d] * A_w[r, d] via MFMA.
// Block = 256 thr (4 waves) on 16 rows. K-loop BK=256: x staged to LDS with
// COALESCED global reads (16 lanes x 16B contiguous per row), split to bf16
// hi/lo, XOR-swizzled (full-address byte ^= (row&7)<<4, SAME formula on both
// write and read sides -- rule #21). Waves k-split the chunk. Cross-wave
// reduce through LDS, then emit sh prepacked: shp[blk][lane][8].
// ---------------------------------------------------------------------------
__global__ __launch_bounds__(256) void k_sharedM(
    const void* __restrict__ xv, const void* __restrict__ Awv,
    const u16* __restrict__ Aph, const u16* __restrict__ Apl,
    const int* __restrict__ flag, u16* __restrict__ sh2h,
    u16* __restrict__ sh2l) {
  __shared__ u16 xh[4096];               // [16][256] bf16 hi, swizzled
  __shared__ u16 xl[4096];               // lo plane
  __shared__ float red[4][512];          // [wave][row*32 + r]
  int bf = *flag;
  int t = threadIdx.x;
  int lane = t & 63;
  int wave = t >> 6;
  int m = lane & 15, kg = lane >> 4;
  int row0 = blockIdx.x * 16;
  f32x4 acc0 = {0.f, 0.f, 0.f, 0.f};
  f32x4 acc1 = {0.f, 0.f, 0.f, 0.f};
  if (bf) {
    // direct-global path for bf16 inputs (wave w owns contiguous D/4 chunk)
    int kbase = wave * 1024 + kg * 8;
    const u16* xp = (const u16*)xv + (size_t)(row0 + m) * D_ + kbase;
    const u16* a0 = (const u16*)Awv + (size_t)m * D_ + kbase;
    const u16* a1 = (const u16*)Awv + (size_t)(m + 16) * D_ + kbase;
#pragma unroll 4
    for (int k0 = 0; k0 < 1024; k0 += 32) {
      s16x8 a  = *(const s16x8*)(xp + k0);
      s16x8 b0 = *(const s16x8*)(a0 + k0);
      s16x8 b1 = *(const s16x8*)(a1 + k0);
      acc0 = __builtin_amdgcn_mfma_f32_16x16x32_bf16(a, b0, acc0, 0, 0, 0);
      acc1 = __builtin_amdgcn_mfma_f32_16x16x32_bf16(a, b1, acc1, 0, 0, 0);
    }
  } else {
    int srow = t >> 4;                   // staging row 0..15
    int sq = t & 15;                     // staging quad 0..15
    const float* xrow = (const float*)xv + (size_t)(row0 + srow) * D_;
    for (int kc = 0; kc < D_; kc += 256) {
      __syncthreads();                   // protect previous iter's reads
#pragma unroll
      for (int q = 0; q < 4; q++) {
        int colf = (sq + q * 16) * 4;    // float col within chunk
        f32x4 v = *(const f32x4*)(xrow + kc + colf);
        ushort4 h, l;
        split2(v[0], &h.x, &l.x); split2(v[1], &h.y, &l.y);
        split2(v[2], &h.z, &l.z); split2(v[3], &h.w, &l.w);
        // XOR applied to the FULL byte address (matches read side exactly)
        int swz = (srow * 512 + colf * 2) ^ ((srow & 7) << 4);
        *(ushort4*)((char*)xh + swz) = h;
        *(ushort4*)((char*)xl + swz) = l;
      }
      __syncthreads();
#pragma unroll
      for (int p = 0; p < 2; p++) {
        int k32 = (wave * 2 + p) * 32;   // this wave's k sub-chunk
        int boff = (m * 512 + (k32 + kg * 8) * 2) ^ ((m & 7) << 4);
        s16x8 ah = *(const s16x8*)((const char*)xh + boff);
        s16x8 al = *(const s16x8*)((const char*)xl + boff);
        size_t k32idx = (size_t)(kc >> 5) + wave * 2 + p;
        const u16* ph = Aph + (k32idx * 2) * 512;     // [half][lane][8]
        const u16* pl = Apl + (k32idx * 2) * 512;
        s16x8 bh0 = *(const s16x8*)(ph + (size_t)lane * 8);
        s16x8 bl0 = *(const s16x8*)(pl + (size_t)lane * 8);
        s16x8 bh1 = *(const s16x8*)(ph + 512 + (size_t)lane * 8);
        s16x8 bl1 = *(const s16x8*)(pl + 512 + (size_t)lane * 8);
        acc0 = __builtin_amdgcn_mfma_f32_16x16x32_bf16(ah, bh0, acc0, 0, 0, 0);
        acc0 = __builtin_amdgcn_mfma_f32_16x16x32_bf16(ah, bl0, acc0, 0, 0, 0);
        acc0 = __builtin_amdgcn_mfma_f32_16x16x32_bf16(al, bh0, acc0, 0, 0, 0);
        acc1 = __builtin_amdgcn_mfma_f32_16x16x32_bf16(ah, bh1, acc1, 0, 0, 0);
        acc1 = __builtin_amdgcn_mfma_f32_16x16x32_bf16(ah, bl1, acc1, 0, 0, 0);
        acc1 = __builtin_amdgcn_mfma_f32_16x16x32_bf16(al, bh1, acc1, 0, 0, 0);
      }
    }
    __syncthreads();                     // xh/xl done before red reuse below
  }
  // deposit wave partials: C layout col(r)=lane&15, row=(lane>>4)*4+j
  int crow = (lane >> 4) * 4, ccol = lane & 15;
#pragma unroll
  for (int j = 0; j < 4; j++) {
    red[wave][(crow + j) * 32 + ccol]      = acc0[j];
    red[wave][(crow + j) * 32 + ccol + 16] = acc1[j];
  }
  __syncthreads();
  // reduce 4 planes, split to bf16 hi/lo, store PREPACKED fragment order:
  // shp[blk][lane][8]: lane = (r>>3)*16 + row, j = r&7
#pragma unroll
  for (int q = 0; q < 2; q++) {
    int e = t + q * 256;
    float s = red[0][e] + red[1][e] + red[2][e] + red[3][e];
    u16 h, l;
    split2(s, &h, &l);
    int row = e >> 5, r = e & 31;
    size_t dst = (size_t)blockIdx.x * 512 + ((size_t)(r >> 3) * 16 + row) * 8 + (r & 7);
    sh2h[dst] = h;
    sh2l[dst] = l;
  }
}

// ---------------------------------------------------------------------------
// Kernel 6: out[row, o] = sum_r shared[row, r] * Wc[b, o, r] via MFMA.
// Block = 16 rows x full O (contiguous 256 KB output footprint). Per 512-o
// chunk: 32 tiles (8/wave), 3 split-MFMAs each, C into padded LDS [16][516],
// then coalesced streaming stores (1 KB contiguous per instruction).
// All fragment loads are prepacked: base + lane*8.
// ---------------------------------------------------------------------------
#define OCH 512
__global__ __launch_bounds__(256) void k_outM(
    const u16* __restrict__ sh2h, const u16* __restrict__ sh2l,
    const u16* __restrict__ Wph, const u16* __restrict__ Wpl,
    const int* __restrict__ flag, void* __restrict__ out) {
  __shared__ float C[16][516];
  int bf = *flag;
  int t = threadIdx.x;
  int lane = t & 63, wave = t >> 6;
  int row0 = blockIdx.x * 16;
  int b = row0 >> 11;
  int m = lane & 15;
  // A fragments (prepacked per 16-row block)
  s16x8 Ah = *(const s16x8*)(sh2h + (size_t)blockIdx.x * 512 + (size_t)lane * 8);
  s16x8 Al = *(const s16x8*)(sh2l + (size_t)blockIdx.x * 512 + (size_t)lane * 8);
  int crow = (lane >> 4) * 4;
  const u16* whB = Wph + (size_t)b * 131072;   // 256 tiles * 512
  const u16* wlB = Wpl + (size_t)b * 131072;
  for (int oc = 0; oc < O_; oc += OCH) {
#pragma unroll
    for (int i = 0; i < 8; i++) {
      int otc = wave * 8 + i;                  // tile within chunk 0..31
      size_t otg = (size_t)((oc >> 4) + otc);  // global tile
      s16x8 Bh = *(const s16x8*)(whB + otg * 512 + (size_t)lane * 8);
      s16x8 Bl = *(const s16x8*)(wlB + otg * 512 + (size_t)lane * 8);
      f32x4 acc = {0.f, 0.f, 0.f, 0.f};
      acc = __builtin_amdgcn_mfma_f32_16x16x32_bf16(Ah, Bh, acc, 0, 0, 0);
      acc = __builtin_amdgcn_mfma_f32_16x16x32_bf16(Ah, Bl, acc, 0, 0, 0);
      acc = __builtin_amdgcn_mfma_f32_16x16x32_bf16(Al, Bh, acc, 0, 0, 0);
      int ocol = otc * 16 + m;                 // col within chunk
#pragma unroll
      for (int j = 0; j < 4; j++) C[crow + j][ocol] = acc[j];
    }
    __syncthreads();
    // stream 16 rows x 2KB: per iter 2 rows, 1KB contiguous per wave-instr
#pragma unroll
    for (int it = 0; it < 8; it++) {
      int row = it * 2 + (t >> 7);
      int col = (t & 127) * 4;
      f32x4 v = *(const f32x4*)&C[row][col];
      size_t off = (size_t)(row0 + row) * O_ + oc + col;
      if (bf) {
        ushort4 o4;
        o4.x = f2b(v[0]); o4.y = f2b(v[1]); o4.z = f2b(v[2]); o4.w = f2b(v[3]);
        *(ushort4*)((u16*)out + off) = o4;
      } else {
        *(f32x4*)((float*)out + off) = v;
      }
    }
    __syncthreads();                           // C reuse next chunk
  }
}

// ---------------------------------------------------------------------------
extern "C" void kernel_launch(void* const* d_in, const int* in_sizes, int n_in,
                              void* d_out, int out_size, void* d_ws, size_t ws_size,
                              hipStream_t stream) {
  const void* x       = d_in[0];                 // [4,2048,4096] f32 or bf16
  const int*  eof     = (const int*)d_in[1];     // [4]
  const void* noise   = d_in[2];                 // [4,8]
  const void* Aw      = d_in[3];                 // [32,4096]
  const void* Bw      = d_in[4];                 // [8,4096,32]
  const void* route_w = d_in[5];                 // [8,4096]
  const void* noise_w = d_in[6];                 // [8,4096]
  float* wsf = (float*)d_ws;
  int* flag = (int*)wsf;                         // wsf[0]
  float* gates = wsf + 80;
  // u16 regions after the 112-float scalar header (448 B, 16B-aligned)
  u16* Wph  = (u16*)(wsf + 112);                 // 524288 u16 = 1 MB
  u16* Wpl  = Wph + (size_t)B_ * O_ * R_;        // 1 MB
  u16* Aph  = Wpl + (size_t)B_ * O_ * R_;        // 131072 u16 = 256 KB
  u16* Apl  = Aph + (size_t)R_ * D_;             // 256 KB
  u16* sh2h = Apl + (size_t)R_ * D_;             // 262144 u16 = 512 KB
  u16* sh2l = sh2h + (size_t)B_ * S_ * R_;       // 512 KB

  k_detect<<<1, 64, 0, stream>>>((const unsigned int*)x, flag);
  k_logits<<<B_ * E_, 256, 0, stream>>>(x, eof, route_w, noise_w, flag, wsf);
  k_gates<<<1, 64, 0, stream>>>(noise, flag, wsf);
  k_prepA<<<64, 256, 0, stream>>>((const float*)Aw, flag, Aph, Apl);
  k_wc<<<(B_ * O_ * R_ / 4) / 256, 256, 0, stream>>>(Bw, flag, gates, Wph, Wpl);
  k_sharedM<<<(B_ * S_) / 16, 256, 0, stream>>>(x, Aw, Aph, Apl, flag, sh2h, sh2l);
  k_outM<<<(B_ * S_) / 16, 256, 0, stream>>>(sh2h, sh2l, Wph, Wpl, flag, d_out);
}

// Round 6
// 303.555 us; speedup vs baseline: 2.1820x; 1.0382x over previous
//
#include <hip/hip_runtime.h>
#include <stdint.h>
#include <math.h>

#define B_ 4
#define S_ 2048
#define D_ 4096
#define O_ 4096
#define E_ 8
#define R_ 32
#define SCALING 2.0f
#define NOISE_EPS 0.01f

typedef unsigned short u16;
typedef short s16x8 __attribute__((ext_vector_type(8)));   // 8 bf16 = 4 VGPRs
typedef float f32x4 __attribute__((ext_vector_type(4)));

__device__ __forceinline__ float b2f(u16 u) {
  union { unsigned int i; float f; } v; v.i = ((unsigned int)u) << 16; return v.f;
}
__device__ __forceinline__ u16 f2b(float f) {
  union { unsigned int i; float f; } v; v.f = f;
  unsigned int i = v.i;
  return (u16)((i + 0x7FFFu + ((i >> 16) & 1u)) >> 16);  // RNE
}
// two-term bf16 split: f = b2f(h) + b2f(l) + O(2^-17 |f|)
__device__ __forceinline__ void split2(float f, u16* h, u16* l) {
  u16 hi = f2b(f);
  *h = hi;
  *l = f2b(f - b2f(hi));   // f - b2f(hi) is exact in fp32
}

__device__ __forceinline__ float ld(const void* p, size_t i, int bf) {
  return bf ? b2f(((const u16*)p)[i]) : ((const float*)p)[i];
}

// ---------------------------------------------------------------------------
// Kernel 0: detect dtype of float inputs by inspecting x's bit patterns.
// ---------------------------------------------------------------------------
__global__ void k_detect(const unsigned int* __restrict__ xw, int* __restrict__ flag) {
  __shared__ int cnt;
  if (threadIdx.x == 0) cnt = 0;
  __syncthreads();
  unsigned int w = xw[threadIdx.x];
  unsigned int e = (w >> 7) & 0xFFu;
  if (e >= 90u && e <= 140u) atomicAdd(&cnt, 1);
  __syncthreads();
  if (threadIdx.x == 0) *flag = (cnt > 48) ? 1 : 0;
}

// ---------------------------------------------------------------------------
// Kernel 1: clean/noise logits. One block per (b,e).
// ---------------------------------------------------------------------------
__global__ __launch_bounds__(256) void k_logits(
    const void* __restrict__ x, const int* __restrict__ eof,
    const void* __restrict__ route_w, const void* __restrict__ noise_w,
    const int* __restrict__ flag, float* __restrict__ wsf) {
  int bf = *flag;
  int be = blockIdx.x;            // 0..31
  int b = be >> 3, e = be & 7;
  size_t xoff = ((size_t)b * S_ + (size_t)eof[b]) * D_;
  size_t woff = (size_t)e * D_;
  float ac = 0.f, an = 0.f;
  for (int d = threadIdx.x; d < D_; d += 256) {
    float xv = ld(x, xoff + d, bf);
    ac += xv * ld(route_w, woff + d, bf);
    an += xv * ld(noise_w, woff + d, bf);
  }
  __shared__ float rc[256], rn[256];
  rc[threadIdx.x] = ac; rn[threadIdx.x] = an;
  __syncthreads();
  for (int s = 128; s > 0; s >>= 1) {
    if (threadIdx.x < (unsigned)s) {
      rc[threadIdx.x] += rc[threadIdx.x + s];
      rn[threadIdx.x] += rn[threadIdx.x + s];
    }
    __syncthreads();
  }
  if (threadIdx.x == 0) { wsf[16 + be] = rc[0]; wsf[48 + be] = rn[0]; }
}

// ---------------------------------------------------------------------------
// Kernel 2: noisy top-2 softmax gates.
// ---------------------------------------------------------------------------
__global__ void k_gates(const void* __restrict__ noise, const int* __restrict__ flag,
                        float* __restrict__ wsf) {
  int bf = *flag;
  int b = threadIdx.x;
  if (b >= B_) return;
  float lg[E_];
  for (int e = 0; e < E_; e++) {
    float c = wsf[16 + b * 8 + e];
    float n = wsf[48 + b * 8 + e];
    float sp = (n > 20.f) ? n : log1pf(expf(n));   // softplus
    lg[e] = c + ld(noise, b * 8 + e, bf) * (sp + NOISE_EPS);
  }
  int i1 = 0; float v1 = lg[0];
  for (int e = 1; e < E_; e++) if (lg[e] > v1) { v1 = lg[e]; i1 = e; }
  int i2 = -1; float v2 = -3.0e38f;
  for (int e = 0; e < E_; e++) if (e != i1 && lg[e] > v2) { v2 = lg[e]; i2 = e; }
  float t = expf(v2 - v1);              // v2 <= v1, stable
  float g1 = 1.f / (1.f + t);
  float g2 = t / (1.f + t);
  for (int e = 0; e < E_; e++) wsf[80 + b * 8 + e] = 0.f;
  wsf[80 + b * 8 + i1] = g1;
  wsf[80 + b * 8 + i2] = g2;
}

// ---------------------------------------------------------------------------
// Kernel 3 (fused prep): blocks [0,512) = Wc planes; blocks [512,576) = A
// planes (fp32 path only). Both emit PREPACKED fragment-order bf16 hi/lo.
// Wc: Wp[b][ot][lane][8], ot=o>>4, lane=(r>>3)*16+(o&15), j=r&7.
// A : Ap[k32idx][half][lane][8], r=half*16+(lane&15), d=k32idx*32+(lane>>4)*8+j.
// ---------------------------------------------------------------------------
__global__ __launch_bounds__(256) void k_prep(
    const void* __restrict__ Bw, const float* __restrict__ Aw,
    const int* __restrict__ flag, const float* __restrict__ gates,
    u16* __restrict__ Wph, u16* __restrict__ Wpl,
    u16* __restrict__ Aph, u16* __restrict__ Apl) {
  int bf = *flag;
  int blk = blockIdx.x;
  if (blk < 512) {
    int idx = blk * 256 + threadIdx.x;            // 0 .. 131071
    int b = idx >> 15;
    int u = idx & 32767;                          // o*8 + rq
    int o = u >> 3, rq = u & 7;
    float g[E_];
#pragma unroll
    for (int e = 0; e < E_; e++) g[e] = gates[b * 8 + e];
    f32x4 acc = {0.f, 0.f, 0.f, 0.f};
    if (bf) {
#pragma unroll
      for (int e = 0; e < E_; e++) {
        ushort4 v = ((const ushort4*)Bw)[(size_t)e * 32768 + u];
        acc[0] += g[e] * b2f(v.x);
        acc[1] += g[e] * b2f(v.y);
        acc[2] += g[e] * b2f(v.z);
        acc[3] += g[e] * b2f(v.w);
      }
    } else {
#pragma unroll
      for (int e = 0; e < E_; e++) {
        f32x4 v = ((const f32x4*)Bw)[(size_t)e * 32768 + u];
        acc += g[e] * v;
      }
    }
    acc *= SCALING;
    ushort4 h, l;
    split2(acc[0], &h.x, &l.x); split2(acc[1], &h.y, &l.y);
    split2(acc[2], &h.z, &l.z); split2(acc[3], &h.w, &l.w);
    int ot = o >> 4;
    int lane = ((rq >> 1) * 16) + (o & 15);
    size_t base = (((size_t)b * 256 + ot) * 64 + lane) * 8 + (rq & 1) * 4;
    *(ushort4*)(Wph + base) = h;
    *(ushort4*)(Wpl + base) = l;
  } else {
    if (bf) return;                               // bf16 inputs: A_w used directly
    int flat = (blk - 512) * 256 + threadIdx.x;   // 0 .. 16383
    int k32idx = flat >> 7;
    int rem = flat & 127;
    int hf = rem >> 6;
    int lane = rem & 63;
    int r = hf * 16 + (lane & 15);
    int d = k32idx * 32 + (lane >> 4) * 8;
    const float* src = Aw + (size_t)r * D_ + d;
    f32x4 v0 = *(const f32x4*)src;
    f32x4 v1 = *(const f32x4*)(src + 4);
    ushort4 h0, l0, h1, l1;
    split2(v0[0], &h0.x, &l0.x); split2(v0[1], &h0.y, &l0.y);
    split2(v0[2], &h0.z, &l0.z); split2(v0[3], &h0.w, &l0.w);
    split2(v1[0], &h1.x, &l1.x); split2(v1[1], &h1.y, &l1.y);
    split2(v1[2], &h1.z, &l1.z); split2(v1[3], &h1.w, &l1.w);
    *(ushort4*)(Aph + (size_t)flat * 8)     = h0;
    *(ushort4*)(Aph + (size_t)flat * 8 + 4) = h1;
    *(ushort4*)(Apl + (size_t)flat * 8)     = l0;
    *(ushort4*)(Apl + (size_t)flat * 8 + 4) = l1;
  }
}

// ---------------------------------------------------------------------------
// Kernel 4 (MEGA, fused sharedM+outM): block = 16 rows.
// Phase 1: sh[16 rows][32 r] = x . A^T via MFMA (bf16 split path for fp32
//   inputs; direct for bf16 inputs). Cross-wave LDS reduce, pack fragments
//   into LDS (shAh/shAl) -- no global round trip.
// Phase 2: out[16 rows][all O] = sh . Wc^T via MFMA, C staged in LDS,
//   coalesced streaming stores.
// LDS: phase-1 buffers union'd with phase-2 C (35 KB total -> 4 blocks/CU).
// ---------------------------------------------------------------------------
#define OCH 512
__global__ __launch_bounds__(256) void k_mega(
    const void* __restrict__ xv, const void* __restrict__ Awv,
    const u16* __restrict__ Aph, const u16* __restrict__ Apl,
    const u16* __restrict__ Wph, const u16* __restrict__ Wpl,
    const int* __restrict__ flag, void* __restrict__ out) {
  __shared__ union SM {
    struct { u16 xh[4096]; u16 xl[4096]; float red[4][512]; } p1;  // 24 KB
    float C[16][516];                                              // 33 KB
  } sm;
  __shared__ u16 shAh[512], shAl[512];   // packed sh fragments (2 KB)
  int bf = *flag;
  int t = threadIdx.x;
  int lane = t & 63;
  int wave = t >> 6;
  int m = lane & 15, kg = lane >> 4;
  int row0 = blockIdx.x * 16;
  int b = row0 >> 11;

  // ---------------- Phase 1: shared projection ----------------
  f32x4 acc0 = {0.f, 0.f, 0.f, 0.f};
  f32x4 acc1 = {0.f, 0.f, 0.f, 0.f};
  if (bf) {
    // direct-global path for bf16 inputs (wave w owns contiguous D/4 chunk)
    int kbase = wave * 1024 + kg * 8;
    const u16* xp = (const u16*)xv + (size_t)(row0 + m) * D_ + kbase;
    const u16* a0 = (const u16*)Awv + (size_t)m * D_ + kbase;
    const u16* a1 = (const u16*)Awv + (size_t)(m + 16) * D_ + kbase;
#pragma unroll 4
    for (int k0 = 0; k0 < 1024; k0 += 32) {
      s16x8 a  = *(const s16x8*)(xp + k0);
      s16x8 b0 = *(const s16x8*)(a0 + k0);
      s16x8 b1 = *(const s16x8*)(a1 + k0);
      acc0 = __builtin_amdgcn_mfma_f32_16x16x32_bf16(a, b0, acc0, 0, 0, 0);
      acc1 = __builtin_amdgcn_mfma_f32_16x16x32_bf16(a, b1, acc1, 0, 0, 0);
    }
  } else {
    int srow = t >> 4;                   // staging row 0..15
    int sq = t & 15;                     // staging quad 0..15
    const float* xrow = (const float*)xv + (size_t)(row0 + srow) * D_;
    for (int kc = 0; kc < D_; kc += 256) {
      __syncthreads();                   // protect previous iter's reads
#pragma unroll
      for (int q = 0; q < 4; q++) {
        int colf = (sq + q * 16) * 4;    // float col within chunk
        f32x4 v = *(const f32x4*)(xrow + kc + colf);
        ushort4 h, l;
        split2(v[0], &h.x, &l.x); split2(v[1], &h.y, &l.y);
        split2(v[2], &h.z, &l.z); split2(v[3], &h.w, &l.w);
        // XOR on the FULL byte address (identical formula on read side)
        int swz = (srow * 512 + colf * 2) ^ ((srow & 7) << 4);
        *(ushort4*)((char*)sm.p1.xh + swz) = h;
        *(ushort4*)((char*)sm.p1.xl + swz) = l;
      }
      __syncthreads();
#pragma unroll
      for (int p = 0; p < 2; p++) {
        int k32 = (wave * 2 + p) * 32;   // this wave's k sub-chunk
        int boff = (m * 512 + (k32 + kg * 8) * 2) ^ ((m & 7) << 4);
        s16x8 ah = *(const s16x8*)((const char*)sm.p1.xh + boff);
        s16x8 al = *(const s16x8*)((const char*)sm.p1.xl + boff);
        size_t k32idx = (size_t)(kc >> 5) + wave * 2 + p;
        const u16* ph = Aph + (k32idx * 2) * 512;     // [half][lane][8]
        const u16* pl = Apl + (k32idx * 2) * 512;
        s16x8 bh0 = *(const s16x8*)(ph + (size_t)lane * 8);
        s16x8 bl0 = *(const s16x8*)(pl + (size_t)lane * 8);
        s16x8 bh1 = *(const s16x8*)(ph + 512 + (size_t)lane * 8);
        s16x8 bl1 = *(const s16x8*)(pl + 512 + (size_t)lane * 8);
        acc0 = __builtin_amdgcn_mfma_f32_16x16x32_bf16(ah, bh0, acc0, 0, 0, 0);
        acc0 = __builtin_amdgcn_mfma_f32_16x16x32_bf16(ah, bl0, acc0, 0, 0, 0);
        acc0 = __builtin_amdgcn_mfma_f32_16x16x32_bf16(al, bh0, acc0, 0, 0, 0);
        acc1 = __builtin_amdgcn_mfma_f32_16x16x32_bf16(ah, bh1, acc1, 0, 0, 0);
        acc1 = __builtin_amdgcn_mfma_f32_16x16x32_bf16(ah, bl1, acc1, 0, 0, 0);
        acc1 = __builtin_amdgcn_mfma_f32_16x16x32_bf16(al, bh1, acc1, 0, 0, 0);
      }
    }
  }
  __syncthreads();                       // xh/xl reads done before red reuse
  // deposit wave partials: C layout col(r)=lane&15, row=(lane>>4)*4+j
  int crow = (lane >> 4) * 4, ccol = lane & 15;
#pragma unroll
  for (int j = 0; j < 4; j++) {
    sm.p1.red[wave][(crow + j) * 32 + ccol]      = acc0[j];
    sm.p1.red[wave][(crow + j) * 32 + ccol + 16] = acc1[j];
  }
  __syncthreads();
  // reduce 4 planes, split to bf16 hi/lo, pack fragments into LDS:
  // shA[lane][8]: lane = (r>>3)*16 + row, j = r&7
#pragma unroll
  for (int q = 0; q < 2; q++) {
    int e = t + q * 256;
    float s = sm.p1.red[0][e] + sm.p1.red[1][e] + sm.p1.red[2][e] + sm.p1.red[3][e];
    u16 h, l;
    split2(s, &h, &l);
    int row = e >> 5, r = e & 31;
    int dst = ((r >> 3) * 16 + row) * 8 + (r & 7);
    shAh[dst] = h;
    shAl[dst] = l;
  }
  __syncthreads();                       // shA ready; p1.red no longer read

  // ---------------- Phase 2: output GEMM ----------------
  s16x8 Ah = *(const s16x8*)(shAh + (size_t)lane * 8);
  s16x8 Al = *(const s16x8*)(shAl + (size_t)lane * 8);
  const u16* whB = Wph + (size_t)b * 131072;   // 256 tiles * 512
  const u16* wlB = Wpl + (size_t)b * 131072;
  for (int oc = 0; oc < O_; oc += OCH) {
    __syncthreads();                     // C free (prev stores / phase-1 LDS)
#pragma unroll
    for (int i = 0; i < 8; i++) {
      int otc = wave * 8 + i;                  // tile within chunk 0..31
      size_t otg = (size_t)((oc >> 4) + otc);  // global tile
      s16x8 Bh = *(const s16x8*)(whB + otg * 512 + (size_t)lane * 8);
      s16x8 Bl = *(const s16x8*)(wlB + otg * 512 + (size_t)lane * 8);
      f32x4 acc = {0.f, 0.f, 0.f, 0.f};
      acc = __builtin_amdgcn_mfma_f32_16x16x32_bf16(Ah, Bh, acc, 0, 0, 0);
      acc = __builtin_amdgcn_mfma_f32_16x16x32_bf16(Ah, Bl, acc, 0, 0, 0);
      acc = __builtin_amdgcn_mfma_f32_16x16x32_bf16(Al, Bh, acc, 0, 0, 0);
      int ocol = otc * 16 + m;                 // col within chunk
#pragma unroll
      for (int j = 0; j < 4; j++) sm.C[crow + j][ocol] = acc[j];
    }
    __syncthreads();
    // stream 16 rows x 2KB: per iter 2 rows, 1KB contiguous per wave-instr
#pragma unroll
    for (int it = 0; it < 8; it++) {
      int row = it * 2 + (t >> 7);
      int col = (t & 127) * 4;
      f32x4 v = *(const f32x4*)&sm.C[row][col];
      size_t off = (size_t)(row0 + row) * O_ + oc + col;
      if (bf) {
        ushort4 o4;
        o4.x = f2b(v[0]); o4.y = f2b(v[1]); o4.z = f2b(v[2]); o4.w = f2b(v[3]);
        *(ushort4*)((u16*)out + off) = o4;
      } else {
        *(f32x4*)((float*)out + off) = v;
      }
    }
  }
}

// ---------------------------------------------------------------------------
extern "C" void kernel_launch(void* const* d_in, const int* in_sizes, int n_in,
                              void* d_out, int out_size, void* d_ws, size_t ws_size,
                              hipStream_t stream) {
  const void* x       = d_in[0];                 // [4,2048,4096] f32 or bf16
  const int*  eof     = (const int*)d_in[1];     // [4]
  const void* noise   = d_in[2];                 // [4,8]
  const void* Aw      = d_in[3];                 // [32,4096]
  const void* Bw      = d_in[4];                 // [8,4096,32]
  const void* route_w = d_in[5];                 // [8,4096]
  const void* noise_w = d_in[6];                 // [8,4096]
  float* wsf = (float*)d_ws;
  int* flag = (int*)wsf;                         // wsf[0]
  float* gates = wsf + 80;
  // u16 regions after the 112-float scalar header (448 B, 16B-aligned)
  u16* Wph  = (u16*)(wsf + 112);                 // 524288 u16 = 1 MB
  u16* Wpl  = Wph + (size_t)B_ * O_ * R_;        // 1 MB
  u16* Aph  = Wpl + (size_t)B_ * O_ * R_;        // 131072 u16 = 256 KB
  u16* Apl  = Aph + (size_t)R_ * D_;             // 256 KB

  k_detect<<<1, 64, 0, stream>>>((const unsigned int*)x, flag);
  k_logits<<<B_ * E_, 256, 0, stream>>>(x, eof, route_w, noise_w, flag, wsf);
  k_gates<<<1, 64, 0, stream>>>(noise, flag, wsf);
  k_prep<<<512 + 64, 256, 0, stream>>>(Bw, (const float*)Aw, flag, gates,
                                       Wph, Wpl, Aph, Apl);
  k_mega<<<(B_ * S_) / 16, 256, 0, stream>>>(x, Aw, Aph, Apl, Wph, Wpl,
                                             flag, d_out);
}

// Round 7
// 285.670 us; speedup vs baseline: 2.3186x; 1.0626x over previous
//
#include <hip/hip_runtime.h>
#include <stdint.h>
#include <math.h>

#define B_ 4
#define S_ 2048
#define D_ 4096
#define O_ 4096
#define E_ 8
#define R_ 32
#define SCALING 2.0f
#define NOISE_EPS 0.01f

typedef unsigned short u16;
typedef short s16x8 __attribute__((ext_vector_type(8)));   // 8 bf16 = 4 VGPRs
typedef float f32x4 __attribute__((ext_vector_type(4)));

__device__ __forceinline__ float b2f(u16 u) {
  union { unsigned int i; float f; } v; v.i = ((unsigned int)u) << 16; return v.f;
}
__device__ __forceinline__ u16 f2b(float f) {
  union { unsigned int i; float f; } v; v.f = f;
  unsigned int i = v.i;
  return (u16)((i + 0x7FFFu + ((i >> 16) & 1u)) >> 16);  // RNE
}
// two-term bf16 split: f = b2f(h) + b2f(l) + O(2^-17 |f|)
__device__ __forceinline__ void split2(float f, u16* h, u16* l) {
  u16 hi = f2b(f);
  *h = hi;
  *l = f2b(f - b2f(hi));   // f - b2f(hi) is exact in fp32
}

__device__ __forceinline__ float ld(const void* p, size_t i, int bf) {
  return bf ? b2f(((const u16*)p)[i]) : ((const float*)p)[i];
}

// Inline dtype probe: every wave reads the same first 64 words of x and
// ballots on "bits 14..7 look like a bf16 exponent". Uniform across waves
// and blocks -> no flag kernel, no cross-kernel dependency.
__device__ __forceinline__ int detect_bf(const unsigned int* __restrict__ xw) {
  unsigned int w = xw[threadIdx.x & 63];
  unsigned int e = (w >> 7) & 0xFFu;
  unsigned long long mask = __ballot((e >= 90u) && (e <= 140u));
  return (__popcll(mask) > 48) ? 1 : 0;
}

// ---------------------------------------------------------------------------
// Kernel 1: clean/noise logits. One block per (b,e). Self-detects dtype.
// ---------------------------------------------------------------------------
__global__ __launch_bounds__(256) void k_logits(
    const void* __restrict__ x, const int* __restrict__ eof,
    const void* __restrict__ route_w, const void* __restrict__ noise_w,
    float* __restrict__ wsf) {
  int bf = detect_bf((const unsigned int*)x);
  int be = blockIdx.x;            // 0..31
  int b = be >> 3, e = be & 7;
  size_t xoff = ((size_t)b * S_ + (size_t)eof[b]) * D_;
  size_t woff = (size_t)e * D_;
  float ac = 0.f, an = 0.f;
  for (int d = threadIdx.x; d < D_; d += 256) {
    float xv = ld(x, xoff + d, bf);
    ac += xv * ld(route_w, woff + d, bf);
    an += xv * ld(noise_w, woff + d, bf);
  }
  __shared__ float rc[256], rn[256];
  rc[threadIdx.x] = ac; rn[threadIdx.x] = an;
  __syncthreads();
  for (int s = 128; s > 0; s >>= 1) {
    if (threadIdx.x < (unsigned)s) {
      rc[threadIdx.x] += rc[threadIdx.x + s];
      rn[threadIdx.x] += rn[threadIdx.x + s];
    }
    __syncthreads();
  }
  if (threadIdx.x == 0) { wsf[16 + be] = rc[0]; wsf[48 + be] = rn[0]; }
}

// ---------------------------------------------------------------------------
// Kernel 2 (fused prep): blocks [0,512) = Wc planes (gates recomputed
// per-thread from staged logits -- k_gates kernel eliminated); blocks
// [512,576) = A planes (fp32 path only). PREPACKED fragment-order bf16 hi/lo.
// Wc: Wp[b][ot][lane][8], ot=o>>4, lane=(r>>3)*16+(o&15), j=r&7.
// A : Ap[k32idx][half][lane][8], r=half*16+(lane&15), d=k32idx*32+(lane>>4)*8+j.
// ---------------------------------------------------------------------------
__global__ __launch_bounds__(256) void k_prep(
    const void* __restrict__ Bw, const float* __restrict__ Aw,
    const void* __restrict__ noise, const void* __restrict__ x,
    const float* __restrict__ wsf,
    u16* __restrict__ Wph, u16* __restrict__ Wpl,
    u16* __restrict__ Aph, u16* __restrict__ Apl) {
  int bf = detect_bf((const unsigned int*)x);
  int blk = blockIdx.x;
  if (blk < 512) {
    int idx = blk * 256 + threadIdx.x;            // 0 .. 131071
    int b = idx >> 15;                            // uniform per block
    // --- noisy top-2 gates, recomputed redundantly (cheap, removes launch)
    float lg[E_];
#pragma unroll
    for (int e = 0; e < E_; e++) {
      float c = wsf[16 + b * 8 + e];
      float n = wsf[48 + b * 8 + e];
      float sp = (n > 20.f) ? n : log1pf(expf(n));
      lg[e] = c + ld(noise, b * 8 + e, bf) * (sp + NOISE_EPS);
    }
    int i1 = 0; float v1 = lg[0];
#pragma unroll
    for (int e = 1; e < E_; e++) if (lg[e] > v1) { v1 = lg[e]; i1 = e; }
    int i2 = -1; float v2 = -3.0e38f;
#pragma unroll
    for (int e = 0; e < E_; e++) if (e != i1 && lg[e] > v2) { v2 = lg[e]; i2 = e; }
    float tt = expf(v2 - v1);
    float g1 = 1.f / (1.f + tt);
    float g2 = tt / (1.f + tt);
    float g[E_];
#pragma unroll
    for (int e = 0; e < E_; e++) g[e] = 0.f;
    g[i1] = g1; g[i2] = g2;
    // --- Wc accumulation
    int u = idx & 32767;                          // o*8 + rq
    int o = u >> 3, rq = u & 7;
    f32x4 acc = {0.f, 0.f, 0.f, 0.f};
    if (bf) {
#pragma unroll
      for (int e = 0; e < E_; e++) {
        ushort4 v = ((const ushort4*)Bw)[(size_t)e * 32768 + u];
        acc[0] += g[e] * b2f(v.x);
        acc[1] += g[e] * b2f(v.y);
        acc[2] += g[e] * b2f(v.z);
        acc[3] += g[e] * b2f(v.w);
      }
    } else {
#pragma unroll
      for (int e = 0; e < E_; e++) {
        f32x4 v = ((const f32x4*)Bw)[(size_t)e * 32768 + u];
        acc += g[e] * v;
      }
    }
    acc *= SCALING;
    ushort4 h, l;
    split2(acc[0], &h.x, &l.x); split2(acc[1], &h.y, &l.y);
    split2(acc[2], &h.z, &l.z); split2(acc[3], &h.w, &l.w);
    int ot = o >> 4;
    int lane = ((rq >> 1) * 16) + (o & 15);
    size_t base = (((size_t)b * 256 + ot) * 64 + lane) * 8 + (rq & 1) * 4;
    *(ushort4*)(Wph + base) = h;
    *(ushort4*)(Wpl + base) = l;
  } else {
    if (bf) return;                               // bf16 inputs: A_w used directly
    int flat = (blk - 512) * 256 + threadIdx.x;   // 0 .. 16383
    int k32idx = flat >> 7;
    int rem = flat & 127;
    int hf = rem >> 6;
    int lane = rem & 63;
    int r = hf * 16 + (lane & 15);
    int d = k32idx * 32 + (lane >> 4) * 8;
    const float* src = Aw + (size_t)r * D_ + d;
    f32x4 v0 = *(const f32x4*)src;
    f32x4 v1 = *(const f32x4*)(src + 4);
    ushort4 h0, l0, h1, l1;
    split2(v0[0], &h0.x, &l0.x); split2(v0[1], &h0.y, &l0.y);
    split2(v0[2], &h0.z, &l0.z); split2(v0[3], &h0.w, &l0.w);
    split2(v1[0], &h1.x, &l1.x); split2(v1[1], &h1.y, &l1.y);
    split2(v1[2], &h1.z, &l1.z); split2(v1[3], &h1.w, &l1.w);
    *(ushort4*)(Aph + (size_t)flat * 8)     = h0;
    *(ushort4*)(Aph + (size_t)flat * 8 + 4) = h1;
    *(ushort4*)(Apl + (size_t)flat * 8)     = l0;
    *(ushort4*)(Apl + (size_t)flat * 8 + 4) = l1;
  }
}

// ---------------------------------------------------------------------------
// Kernel 3: partial shared projection via MFMA, D split 4 ways for occupancy.
// Block (rowgrp, dq) = 16 rows x 1024 k. Grid 2048 -> 8 blocks/CU (32 w/CU).
// fp32 path: x staged+split to swizzled LDS (4 chunks of 256 k, short
// barrier chain); bf16 path: direct fragment loads.
// Output: fp32 partials, prepacked fragment order p[rowgrp][dq][lane][8]
// (lane = (r>>3)*16 + row, j = r&7) -- consumer sums 4 dq and splits.
// ---------------------------------------------------------------------------
__global__ __launch_bounds__(256) void k_sharedP(
    const void* __restrict__ xv, const void* __restrict__ Awv,
    const u16* __restrict__ Aph, const u16* __restrict__ Apl,
    float* __restrict__ pbuf) {
  __shared__ union {
    struct { u16 xh[4096]; u16 xl[4096]; } s;    // 16 KB staging
    float red4[4][512];                          // 8 KB reduce (after staging)
  } sm;
  int bf = detect_bf((const unsigned int*)xv);
  int t = threadIdx.x;
  int lane = t & 63;
  int wave = t >> 6;
  int m = lane & 15, kg = lane >> 4;
  int rowgrp = blockIdx.x >> 2;
  int dq = blockIdx.x & 3;
  int row0 = rowgrp * 16;
  f32x4 acc0 = {0.f, 0.f, 0.f, 0.f};
  f32x4 acc1 = {0.f, 0.f, 0.f, 0.f};
  if (bf) {
    // wave owns contiguous 256-k strip of this block's 1024-k range
    int kbase = dq * 1024 + wave * 256 + kg * 8;
    const u16* xp = (const u16*)xv + (size_t)(row0 + m) * D_ + kbase;
    const u16* a0 = (const u16*)Awv + (size_t)m * D_ + kbase;
    const u16* a1 = (const u16*)Awv + (size_t)(m + 16) * D_ + kbase;
#pragma unroll
    for (int k0 = 0; k0 < 256; k0 += 32) {
      s16x8 a  = *(const s16x8*)(xp + k0);
      s16x8 b0 = *(const s16x8*)(a0 + k0);
      s16x8 b1 = *(const s16x8*)(a1 + k0);
      acc0 = __builtin_amdgcn_mfma_f32_16x16x32_bf16(a, b0, acc0, 0, 0, 0);
      acc1 = __builtin_amdgcn_mfma_f32_16x16x32_bf16(a, b1, acc1, 0, 0, 0);
    }
  } else {
    int srow = t >> 4;                   // staging row 0..15
    int sq = t & 15;                     // staging quad 0..15
    const float* xrow = (const float*)xv + (size_t)(row0 + srow) * D_ + dq * 1024;
    for (int c = 0; c < 4; c++) {
      __syncthreads();                   // protect previous iter's reads
#pragma unroll
      for (int q = 0; q < 4; q++) {
        int colf = (sq + q * 16) * 4;    // float col within 256-chunk
        f32x4 v = *(const f32x4*)(xrow + c * 256 + colf);
        ushort4 h, l;
        split2(v[0], &h.x, &l.x); split2(v[1], &h.y, &l.y);
        split2(v[2], &h.z, &l.z); split2(v[3], &h.w, &l.w);
        // XOR on FULL byte address; identical formula on read side (rule 21)
        int swz = (srow * 512 + colf * 2) ^ ((srow & 7) << 4);
        *(ushort4*)((char*)sm.s.xh + swz) = h;
        *(ushort4*)((char*)sm.s.xl + swz) = l;
      }
      __syncthreads();
#pragma unroll
      for (int p2 = 0; p2 < 2; p2++) {
        int k32 = (wave * 2 + p2) * 32;  // this wave's k sub-chunk in [0,256)
        int boff = (m * 512 + (k32 + kg * 8) * 2) ^ ((m & 7) << 4);
        s16x8 ah = *(const s16x8*)((const char*)sm.s.xh + boff);
        s16x8 al = *(const s16x8*)((const char*)sm.s.xl + boff);
        int k32idx = dq * 32 + c * 8 + wave * 2 + p2;
        const u16* ph = Aph + (size_t)k32idx * 1024;  // [half][lane][8]
        const u16* pl = Apl + (size_t)k32idx * 1024;
        s16x8 bh0 = *(const s16x8*)(ph + (size_t)lane * 8);
        s16x8 bl0 = *(const s16x8*)(pl + (size_t)lane * 8);
        s16x8 bh1 = *(const s16x8*)(ph + 512 + (size_t)lane * 8);
        s16x8 bl1 = *(const s16x8*)(pl + 512 + (size_t)lane * 8);
        acc0 = __builtin_amdgcn_mfma_f32_16x16x32_bf16(ah, bh0, acc0, 0, 0, 0);
        acc0 = __builtin_amdgcn_mfma_f32_16x16x32_bf16(ah, bl0, acc0, 0, 0, 0);
        acc0 = __builtin_amdgcn_mfma_f32_16x16x32_bf16(al, bh0, acc0, 0, 0, 0);
        acc1 = __builtin_amdgcn_mfma_f32_16x16x32_bf16(ah, bh1, acc1, 0, 0, 0);
        acc1 = __builtin_amdgcn_mfma_f32_16x16x32_bf16(ah, bl1, acc1, 0, 0, 0);
        acc1 = __builtin_amdgcn_mfma_f32_16x16x32_bf16(al, bh1, acc1, 0, 0, 0);
      }
    }
  }
  __syncthreads();                       // staging reads done before red reuse
  // deposit wave partials: C layout col(r)=lane&15, row=(lane>>4)*4+j
  int crow = (lane >> 4) * 4, ccol = lane & 15;
#pragma unroll
  for (int j = 0; j < 4; j++) {
    sm.red4[wave][(crow + j) * 32 + ccol]      = acc0[j];
    sm.red4[wave][(crow + j) * 32 + ccol + 16] = acc1[j];
  }
  __syncthreads();
  // one wave reduces 4 planes and stores fp32 partials prepacked:
  // thread t = rq*16 + row owns sh[row][rq*8 .. rq*8+7] -> dst = t*8 + j
  if (t < 64) {
    int row = t & 15, rq = t >> 4;
    f32x4 va, vb;
#pragma unroll
    for (int j = 0; j < 4; j++) {
      int e = row * 32 + rq * 8 + j;
      va[j] = sm.red4[0][e] + sm.red4[1][e] + sm.red4[2][e] + sm.red4[3][e];
    }
#pragma unroll
    for (int j = 0; j < 4; j++) {
      int e = row * 32 + rq * 8 + 4 + j;
      vb[j] = sm.red4[0][e] + sm.red4[1][e] + sm.red4[2][e] + sm.red4[3][e];
    }
    float* pp = pbuf + ((size_t)rowgrp * 4 + dq) * 512 + t * 8;
    *(f32x4*)pp = va;
    *(f32x4*)(pp + 4) = vb;
  }
}

// ---------------------------------------------------------------------------
// Kernel 4: out[row, o] = sum_r sh[row, r] * Wc[b, o, r] via MFMA.
// Block (rowgrp, oq) = 16 rows x 1024 o. Grid 2048 -> 8 blocks/CU.
// Sums 4 fp32 dq-partials in-register (coalesced 32B/lane), splits to bf16
// hi/lo fragments once, then 4 chunks of 256 o: 3-MFMA tiles -> LDS C
// [16][260] -> coalesced streaming stores (1 KB/wave-instr).
// ---------------------------------------------------------------------------
__global__ __launch_bounds__(256) void k_outP(
    const void* __restrict__ xv, const float* __restrict__ pbuf,
    const u16* __restrict__ Wph, const u16* __restrict__ Wpl,
    void* __restrict__ out) {
  __shared__ float C[16][260];
  int bf = detect_bf((const unsigned int*)xv);
  int t = threadIdx.x;
  int lane = t & 63, wave = t >> 6, m = lane & 15;
  int rowgrp = blockIdx.x >> 2;
  int oq = blockIdx.x & 3;
  int row0 = rowgrp * 16;
  int b = row0 >> 11;
  // reduce 4 dq-partials, build A fragments
  const float* pp = pbuf + (size_t)rowgrp * 4 * 512;
  f32x4 sa = {0.f, 0.f, 0.f, 0.f}, sb = {0.f, 0.f, 0.f, 0.f};
#pragma unroll
  for (int dq = 0; dq < 4; dq++) {
    sa += *(const f32x4*)(pp + dq * 512 + (size_t)lane * 8);
    sb += *(const f32x4*)(pp + dq * 512 + (size_t)lane * 8 + 4);
  }
  s16x8 Ah, Al;
  {
    u16 h, l;
#pragma unroll
    for (int j = 0; j < 4; j++) {
      split2(sa[j], &h, &l); Ah[j] = (short)h; Al[j] = (short)l;
      split2(sb[j], &h, &l); Ah[4 + j] = (short)h; Al[4 + j] = (short)l;
    }
  }
  int crow = (lane >> 4) * 4;
  const u16* whB = Wph + (size_t)b * 131072;   // 256 tiles * 512
  const u16* wlB = Wpl + (size_t)b * 131072;
  for (int cc = 0; cc < 4; cc++) {
    int tbase = oq * 64 + cc * 16;             // global tile base of chunk
#pragma unroll
    for (int i = 0; i < 4; i++) {
      int otc = wave * 4 + i;                  // tile within chunk 0..15
      size_t otg = (size_t)(tbase + otc);
      s16x8 Bh = *(const s16x8*)(whB + otg * 512 + (size_t)lane * 8);
      s16x8 Bl = *(const s16x8*)(wlB + otg * 512 + (size_t)lane * 8);
      f32x4 acc = {0.f, 0.f, 0.f, 0.f};
      acc = __builtin_amdgcn_mfma_f32_16x16x32_bf16(Ah, Bh, acc, 0, 0, 0);
      acc = __builtin_amdgcn_mfma_f32_16x16x32_bf16(Ah, Bl, acc, 0, 0, 0);
      acc = __builtin_amdgcn_mfma_f32_16x16x32_bf16(Al, Bh, acc, 0, 0, 0);
      int ocol = otc * 16 + m;
#pragma unroll
      for (int j = 0; j < 4; j++) C[crow + j][ocol] = acc[j];
    }
    __syncthreads();
    // stream 16 rows x 1 KB: 4 passes, 4 rows/pass, 1 KB contiguous/wave
#pragma unroll
    for (int pass = 0; pass < 4; pass++) {
      int row = pass * 4 + (t >> 6);
      int col = (t & 63) * 4;
      f32x4 v = *(const f32x4*)&C[row][col];
      size_t off = (size_t)(row0 + row) * O_ + oq * 1024 + cc * 256 + col;
      if (bf) {
        ushort4 o4;
        o4.x = f2b(v[0]); o4.y = f2b(v[1]); o4.z = f2b(v[2]); o4.w = f2b(v[3]);
        *(ushort4*)((u16*)out + off) = o4;
      } else {
        *(f32x4*)((float*)out + off) = v;
      }
    }
    __syncthreads();                           // C reuse next chunk
  }
}

// ---------------------------------------------------------------------------
extern "C" void kernel_launch(void* const* d_in, const int* in_sizes, int n_in,
                              void* d_out, int out_size, void* d_ws, size_t ws_size,
                              hipStream_t stream) {
  const void* x       = d_in[0];                 // [4,2048,4096] f32 or bf16
  const int*  eof     = (const int*)d_in[1];     // [4]
  const void* noise   = d_in[2];                 // [4,8]
  const void* Aw      = d_in[3];                 // [32,4096]
  const void* Bw      = d_in[4];                 // [8,4096,32]
  const void* route_w = d_in[5];                 // [8,4096]
  const void* noise_w = d_in[6];                 // [8,4096]
  float* wsf = (float*)d_ws;
  // ws layout: [16,48) clean logits | [48,80) noise logits | then u16 planes
  u16* Wph  = (u16*)(wsf + 112);                 // 524288 u16 = 1 MB
  u16* Wpl  = Wph + (size_t)B_ * O_ * R_;        // 1 MB
  u16* Aph  = Wpl + (size_t)B_ * O_ * R_;        // 256 KB
  u16* Apl  = Aph + (size_t)R_ * D_;             // 256 KB
  float* pbuf = (float*)(Apl + (size_t)R_ * D_); // 512*4*512 f32 = 4 MB

  k_logits<<<B_ * E_, 256, 0, stream>>>(x, eof, route_w, noise_w, wsf);
  k_prep<<<512 + 64, 256, 0, stream>>>(Bw, (const float*)Aw, noise, x, wsf,
                                       Wph, Wpl, Aph, Apl);
  k_sharedP<<<2048, 256, 0, stream>>>(x, Aw, Aph, Apl, pbuf);
  k_outP<<<2048, 256, 0, stream>>>(x, pbuf, Wph, Wpl, d_out);
}